// Round 9
// baseline (402.257 us; speedup 1.0000x reference)
//
#include <hip/hip_runtime.h>
#include <hip/hip_bf16.h>
#include <hip/hip_cooperative_groups.h>

namespace cg = cooperative_groups;

// ---------------------------------------------------------------------------
// MultiHeadAttention forward on MI355X (gfx950). B=2,S=2048,D=768,H=12,Dh=64.
// Masks scale by +1e-9 (numeric no-op) -> full non-causal softmax; dropped.
//
// Round 14 = round-13 fusion, made un-failable. r13's zero-output forensics:
// absmax err 0.038 == max|ref| -> the cooperative launch silently failed
// (return code unchecked; most likely CooperativeLaunchTooLarge). Fix:
//  * occupancy-adaptive grid (query perCU, launch min(768, perCU*256));
//    every phase is a grid-stride loop -> correct at ANY co-resident size.
//  * checked launch: on ANY error (incl. capture-unsupported) fall back to
//    the verbatim round-12 4-kernel path (same bodies, same ws offsets).
//  * __threadfence() before each grid.sync() (cross-XCD visibility).
// Phase bodies are the r12-verified code: prep / gemm0 128x96 (Q prescaled,
// K, VT 8B-half-swapped) / attn 128-key conflict-free / gemm1 64x64.
// ---------------------------------------------------------------------------

typedef __attribute__((ext_vector_type(8))) short short8;
typedef __attribute__((ext_vector_type(4))) float float4v;
typedef __attribute__((ext_vector_type(8))) _Float16 half8;
typedef __attribute__((ext_vector_type(4))) _Float16 half4;
typedef __attribute__((ext_vector_type(4))) unsigned short ushort4v;

__device__ __forceinline__ void async_copy16(const void* g, void* l) {
  __builtin_amdgcn_global_load_lds(
      (const __attribute__((address_space(1))) void*)g,
      (__attribute__((address_space(3))) void*)l, 16, 0, 0);
}

__device__ __forceinline__ float fast_exp2(float x) {
#if __has_builtin(__builtin_amdgcn_exp2f)
  return __builtin_amdgcn_exp2f(x);
#else
  return exp2f(x);
#endif
}

__device__ __forceinline__ unsigned short f2bf(float v) {
  __hip_bfloat16 h = __float2bfloat16(v);
  unsigned short u;
  __builtin_memcpy(&u, &h, 2);
  return u;
}

#define LOG2E_8 0.18033688011112042f  // log2(e)/8, folded into Q

// ---- prep body: one virtual block of {x cast | weight transpose} -----------
__device__ __forceinline__ void prep_body(
    char* smemraw, int vb, const float* __restrict__ x,
    unsigned short* __restrict__ xb, const float* __restrict__ wqkv,
    __hip_bfloat16* __restrict__ wqkvT, const float* __restrict__ wproj,
    __hip_bfloat16* __restrict__ wprojT) {
  const int tid = threadIdx.x;
  if (vb < 3072) {  // cast: 4096*768 floats, 4/thread
    int i = vb * 256 + tid;
    float4v v = ((const float4v*)x)[i];
    ushort4v o;
#pragma unroll
    for (int r = 0; r < 4; r++) o[r] = f2bf(v[r]);
    ((ushort4v*)xb)[i] = o;
    return;
  }
  float* tile = (float*)smemraw;  // [32][33] f32
  const float* w;
  __hip_bfloat16* wt;
  int N, bx, by;
  if (vb < 4800) {
    int t = vb - 3072; w = wqkv; wt = wqkvT; N = 2304; bx = t % 72; by = t / 72;
  } else {
    int t = vb - 4800; w = wproj; wt = wprojT; N = 768; bx = t % 24; by = t / 24;
  }
  const int n0 = bx * 32, k0 = by * 32;
  const int r = tid >> 5, c = tid & 31;
#pragma unroll
  for (int rr = 0; rr < 32; rr += 8)
    tile[(rr + r) * 33 + c] = w[(long long)(k0 + rr + r) * N + n0 + c];
  __syncthreads();
#pragma unroll
  for (int rr = 0; rr < 32; rr += 8)
    wt[(long long)(n0 + rr + r) * 768 + k0 + c] = __float2bfloat16(tile[c * 33 + rr + r]);
  __syncthreads();  // protect tile for the next grid-stride iteration
}

// ---- bf16 GEMM body, BK=64, K=768 (12 iters), conflict-free XOR swizzle ----
// EPI==0: 128x96 tile; scatter Q(prescaled),K->[B,H,S,64] f16, V->VT (+bias,
//         odd-dh rows 8B-half-swapped: key s at s^4, for attn's V LDS layout).
// EPI==1: 64x64 tile; out f32 [M][768] = acc + bias.
template <int EPI>
__device__ __forceinline__ void gemm_body(
    char* smemraw, int bid,
    const __hip_bfloat16* __restrict__ A, const __hip_bfloat16* __restrict__ Bt,
    const float* __restrict__ bias, float* __restrict__ outF,
    _Float16* __restrict__ Qb, _Float16* __restrict__ Kb,
    _Float16* __restrict__ VT) {
  constexpr int BM = (EPI == 0) ? 128 : 64;
  constexpr int BN = (EPI == 0) ? 96 : 64;
  constexpr int MT = BM / 32;  // 16-tiles per wave (m)
  constexpr int NT = BN / 32;  // 16-tiles per wave (n)
  __hip_bfloat16* At = (__hip_bfloat16*)smemraw;  // BM*64*2 bytes
  __hip_bfloat16* Btl = At + BM * 64;             // BN*64*2 bytes
  const int tid = threadIdx.x;
  const int w = tid >> 6, l = tid & 63;
  const int quad = l >> 4, lane16 = l & 15;
  const int m0 = (EPI == 0) ? (bid & 31) * BM : (bid & 63) * BM;
  const int n0 = (EPI == 0) ? (bid >> 5) * BN : (bid >> 6) * BN;

  float4v acc[MT][NT];
#pragma unroll
  for (int i = 0; i < MT; i++)
#pragma unroll
    for (int j = 0; j < NT; j++) acc[i][j] = float4v{0.f, 0.f, 0.f, 0.f};

  // staging: call c covers rows c*32..c*32+31; thread t -> row c*32+(t>>3),
  // source granule (t&7)^(row&7); dest = base + t*16B
  const int srow = tid >> 3, sgr = tid & 7;
  const __hip_bfloat16* Asrc = A + (long long)(m0 + srow) * 768 + ((sgr ^ (srow & 7)) * 8);
  const __hip_bfloat16* Bsrc = Bt + (long long)(n0 + srow) * 768 + ((sgr ^ (srow & 7)) * 8);
  __hip_bfloat16* Adst = At + tid * 8;
  __hip_bfloat16* Bdst = Btl + tid * 8;

  const int wr = (w >> 1) * (BM / 2), wc = (w & 1) * (BN / 2);
  const int swz = lane16 & 7;

  for (int kt = 0; kt < 12; kt++) {
    const int k0 = kt * 64;
    __syncthreads();
#pragma unroll
    for (int c = 0; c < BM / 32; c++)
      async_copy16(Asrc + (long long)c * 32 * 768 + k0, Adst + c * 2048);
#pragma unroll
    for (int c = 0; c < BN / 32; c++)
      async_copy16(Bsrc + (long long)c * 32 * 768 + k0, Bdst + c * 2048);
    __syncthreads();
#pragma unroll
    for (int h = 0; h < 2; h++) {
      short8 af[MT], bf[NT];
#pragma unroll
      for (int t = 0; t < MT; t++)
        af[t] = *(const short8*)(At + (wr + t * 16 + lane16) * 64 +
                                 (((h * 4 + quad) ^ swz) * 8));
#pragma unroll
      for (int t = 0; t < NT; t++)
        bf[t] = *(const short8*)(Btl + (wc + t * 16 + lane16) * 64 +
                                 (((h * 4 + quad) ^ swz) * 8));
#pragma unroll
      for (int i = 0; i < MT; i++)
#pragma unroll
        for (int j = 0; j < NT; j++)
          acc[i][j] = __builtin_amdgcn_mfma_f32_16x16x32_bf16(af[i], bf[j], acc[i][j], 0, 0, 0);
    }
  }

  // epilogue: C/D layout col=lane16, row=quad*4+reg
#pragma unroll
  for (int i = 0; i < MT; i++) {
    const int mbase = m0 + wr + i * 16 + quad * 4;
#pragma unroll
    for (int j = 0; j < NT; j++) {
      const int n = n0 + wc + j * 16 + lane16;
      const float bv = bias[n];
      if (EPI == 0) {
        const int which = n / 768;  // uniform across the 16-lane tile
        const int rr = n - which * 768;
        const int hh = rr >> 6, dh = rr & 63;
        const float scale = (which == 0) ? LOG2E_8 : 1.0f;
#pragma unroll
        for (int r = 0; r < 4; r++) {
          const int mm = mbase + r;
          const int b = mm >> 11, s = mm & 2047;
          _Float16 val = (_Float16)((acc[i][j][r] + bv) * scale);
          if (which == 0)
            Qb[((long long)(b * 12 + hh) * 2048 + s) * 64 + dh] = val;
          else if (which == 1)
            Kb[((long long)(b * 12 + hh) * 2048 + s) * 64 + dh] = val;
          else
            VT[((long long)(b * 12 + hh) * 64 + dh) * 2048 + (s ^ ((dh & 1) * 4))] = val;
        }
      } else {
#pragma unroll
        for (int r = 0; r < 4; r++)
          outF[(long long)(mbase + r) * 768 + n] = acc[i][j][r] + bv;
      }
    }
  }
}

// ---- attention body, f16, S^T formulation, 128-key tiles -------------------
// 4 waves; wave = 16 q-rows; ctx written bf16 [4096][768]. Conflict-free:
// K slot g^(r&7) (16B granules); V slot8 h^(r&15) (8B granules, via VT's
// pre-swapped odd-dh rows + staged granule j^((row>>1)&7)).
__device__ __forceinline__ void attn_body(
    char* smemraw, int bid, const _Float16* __restrict__ Qb,
    const _Float16* __restrict__ Kb, const _Float16* __restrict__ VT,
    unsigned short* __restrict__ ctx) {
  _Float16* Kl = (_Float16*)smemraw;  // [key(128)][dh(64)]  16 KB
  _Float16* Vl = Kl + 128 * 64;       // [dh(64)][key(128)]  16 KB
  const int tid = threadIdx.x, w = tid >> 6, l = tid & 63;
  const int quad = l >> 4, lane16 = l & 15;
  const int bh = bid >> 5;
  const int q0 = (bid & 31) * 64 + w * 16;
  const _Float16* Qp = Qb + (long long)bh * 2048 * 64;
  const _Float16* Kp = Kb + (long long)bh * 2048 * 64;
  const _Float16* Vp = VT + (long long)bh * 64 * 2048;

  // Q as B-frag of S^T: B[n=q=lane16][k=dh=quad*8+j], two k-halves
  half8 qf[2];
#pragma unroll
  for (int hh = 0; hh < 2; hh++)
    qf[hh] = *(const half8*)(Qp + (q0 + lane16) * 64 + hh * 32 + quad * 8);

  float4v o_acc[4];  // O^T[dh=dt*16+quad*4+r][q=lane16]
#pragma unroll
  for (int t = 0; t < 4; t++) o_acc[t] = float4v{0.f, 0.f, 0.f, 0.f};
  float4v sum_acc = float4v{0.f, 0.f, 0.f, 0.f};  // denominator via mfma(ones,P)
  const half4 ones = {(_Float16)1.f, (_Float16)1.f, (_Float16)1.f, (_Float16)1.f};

  const _Float16* Ksrc = Kp + (long long)(tid >> 3) * 64 + (((tid & 7) ^ ((tid >> 3) & 7)) * 8);
  const _Float16* Vsrc = Vp + (long long)(tid >> 4) * 2048 + (((tid & 15) ^ ((tid >> 5) & 7)) * 8);
  _Float16* Kdst = Kl + tid * 8;
  _Float16* Vdst = Vl + tid * 8;
  const int swz = lane16 & 7;

  for (int kt = 0; kt < 16; kt++) {
    __syncthreads();
#pragma unroll
    for (int c = 0; c < 4; c++) {
      async_copy16(Ksrc + kt * 8192 + c * 2048, Kdst + c * 2048);
      async_copy16(Vsrc + kt * 128 + (long long)c * 16 * 2048, Vdst + c * 2048);
    }
    __syncthreads();

    // S^T = K Q^T : A = K-frag [m=key][k=dh]  (Q carries log2e/8)
    float4v s[8];
#pragma unroll
    for (int kb = 0; kb < 8; kb++) {
      const _Float16* kr = Kl + (kb * 16 + lane16) * 64;
      half8 kf0 = *(const half8*)(kr + ((quad ^ swz) * 8));
      half8 kf1 = *(const half8*)(kr + (((4 + quad) ^ swz) * 8));
      float4v z = float4v{0.f, 0.f, 0.f, 0.f};
      z = __builtin_amdgcn_mfma_f32_16x16x32_f16(kf0, qf[0], z, 0, 0, 0);
      s[kb] = __builtin_amdgcn_mfma_f32_16x16x32_f16(kf1, qf[1], z, 0, 0, 0);
    }
    // p = exp2(s'); P^T packed (pk cvt) as K=16 B-frags (k = quad*4 + r)
    half4 pf[8];
#pragma unroll
    for (int kb = 0; kb < 8; kb++) {
      float p0 = fast_exp2(s[kb][0]);
      float p1 = fast_exp2(s[kb][1]);
      float p2 = fast_exp2(s[kb][2]);
      float p3 = fast_exp2(s[kb][3]);
      auto lo = __builtin_amdgcn_cvt_pkrtz(p0, p1);
      auto hi = __builtin_amdgcn_cvt_pkrtz(p2, p3);
      pf[kb] = half4{static_cast<_Float16>(lo[0]), static_cast<_Float16>(lo[1]),
                     static_cast<_Float16>(hi[0]), static_cast<_Float16>(hi[1])};
    }
    // denominator rows (all rows of D identical = sum over the 16 keys)
#pragma unroll
    for (int kb = 0; kb < 8; kb++)
      sum_acc = __builtin_amdgcn_mfma_f32_16x16x16f16(ones, pf[kb], sum_acc, 0, 0, 0);
    // O^T += V^T P^T : A = V-frag [m=dh][k=key]; true chunk h = kb*4+quad
    // lives at slot8 h^(row&15), row&15 == lane16 -> banks perfectly spread.
#pragma unroll
    for (int dt = 0; dt < 4; dt++) {
      const _Float16* vr = Vl + (dt * 16 + lane16) * 128;
#pragma unroll
      for (int kb = 0; kb < 8; kb++) {
        half4 vf = *(const half4*)(vr + (((kb * 4 + quad) ^ lane16) << 2));
        o_acc[dt] = __builtin_amdgcn_mfma_f32_16x16x16f16(vf, pf[kb], o_acc[dt], 0, 0, 0);
      }
    }
  }
  // every lane already holds the full denominator for its q=lane16
  const float inv = 1.0f / sum_acc[0];
  const int b = bh / 12, hd = bh - (bh / 12) * 12;
  unsigned short* cp = ctx + ((long long)b * 2048 + q0 + lane16) * 768 + hd * 64 + quad * 4;
#pragma unroll
  for (int dt = 0; dt < 4; dt++) {
    ushort4v cv;
#pragma unroll
    for (int r = 0; r < 4; r++) cv[r] = f2bf(o_acc[dt][r] * inv);
    *(ushort4v*)(cp + dt * 16) = cv;
  }
}

// ---- fused cooperative kernel (grid-stride phases, any co-resident grid) ---
__global__ __launch_bounds__(256, 3) void k_fused(
    const float* __restrict__ x, const float* __restrict__ wqkv,
    const float* __restrict__ bqkv, const float* __restrict__ wproj,
    const float* __restrict__ bproj, float* __restrict__ out,
    char* __restrict__ ws) {
  __shared__ __align__(16) char smem[32768];
  __hip_bfloat16* Xb = (__hip_bfloat16*)(ws);                // 4096x768 bf16
  __hip_bfloat16* WqkvT = (__hip_bfloat16*)(ws + 6291456);   // 2304x768 bf16
  __hip_bfloat16* WprojT = (__hip_bfloat16*)(ws + 9830400);  // 768x768 bf16
  _Float16* Qb = (_Float16*)(ws + 11010048);                 // [B,H,S,64] f16
  _Float16* Kb = (_Float16*)(ws + 17301504);
  _Float16* VT = (_Float16*)(ws + 23592960);                 // [B,H,64,S] f16
  unsigned short* ctx = (unsigned short*)(ws + 29884416);    // 4096x768 bf16
  cg::grid_group grid = cg::this_grid();

  for (int vb = blockIdx.x; vb < 5376; vb += gridDim.x)
    prep_body(smem, vb, x, (unsigned short*)Xb, wqkv, WqkvT, wproj, WprojT);
  __threadfence();
  grid.sync();

  for (int vb = blockIdx.x; vb < 768; vb += gridDim.x)
    gemm_body<0>(smem, vb, Xb, WqkvT, bqkv, nullptr, Qb, Kb, VT);
  __threadfence();
  grid.sync();

  for (int vb = blockIdx.x; vb < 768; vb += gridDim.x)
    attn_body(smem, vb, Qb, Kb, VT, ctx);
  __threadfence();
  grid.sync();

  for (int vb = blockIdx.x; vb < 768; vb += gridDim.x)
    gemm_body<1>(smem, vb, (const __hip_bfloat16*)ctx, WprojT, bproj, out,
                 nullptr, nullptr, nullptr);
}

// ---- standalone fallback kernels (verbatim round-12 behavior) --------------
__global__ __launch_bounds__(256) void k_prep_sa(
    const float* __restrict__ x, unsigned short* __restrict__ xb,
    const float* __restrict__ wqkv, __hip_bfloat16* __restrict__ wqkvT,
    const float* __restrict__ wproj, __hip_bfloat16* __restrict__ wprojT) {
  __shared__ __align__(16) char sm[4352];
  prep_body(sm, (int)blockIdx.x, x, xb, wqkv, wqkvT, wproj, wprojT);
}

template <int EPI>
__global__ __launch_bounds__(256) void k_gemm_sa(
    const __hip_bfloat16* __restrict__ A, const __hip_bfloat16* __restrict__ Bt,
    const float* __restrict__ bias, float* __restrict__ outF,
    _Float16* __restrict__ Qb, _Float16* __restrict__ Kb,
    _Float16* __restrict__ VT) {
  __shared__ __align__(16) char sm[(EPI == 0) ? 28672 : 16384];
  gemm_body<EPI>(sm, (int)blockIdx.x, A, Bt, bias, outF, Qb, Kb, VT);
}

__global__ __launch_bounds__(256) void k_attn_sa(
    const _Float16* __restrict__ Qb, const _Float16* __restrict__ Kb,
    const _Float16* __restrict__ VT, unsigned short* __restrict__ ctx) {
  __shared__ __align__(16) char sm[32768];
  attn_body(sm, (int)blockIdx.x, Qb, Kb, VT, ctx);
}

extern "C" void kernel_launch(void* const* d_in, const int* in_sizes, int n_in,
                              void* d_out, int out_size, void* d_ws, size_t ws_size,
                              hipStream_t stream) {
  const float* x = (const float*)d_in[0];
  // d_in[1] attention_mask: masks scaled by +1e-9 -> no-op, dropped
  const float* w_qkv = (const float*)d_in[2];
  const float* b_qkv = (const float*)d_in[3];
  const float* w_proj = (const float*)d_in[4];
  const float* b_proj = (const float*)d_in[5];
  float* out = (float*)d_out;
  char* ws = (char*)d_ws;

  // cooperative path: occupancy-adaptive grid, checked launch
  static int coop_grid = -1;  // -1 uninit, 0 disabled
  if (coop_grid == -1) {
    int perCU = 0;
    hipError_t e = hipOccupancyMaxActiveBlocksPerMultiprocessor(
        &perCU, (const void*)k_fused, 256, 0);
    if (e != hipSuccess || perCU <= 0) {
      coop_grid = 0;
      (void)hipGetLastError();
    } else {
      int g = perCU * 256;  // 256 CUs on MI355X
      coop_grid = g > 768 ? 768 : g;
    }
  }
  if (coop_grid > 0) {
    void* args[] = {(void*)&x, (void*)&w_qkv, (void*)&b_qkv, (void*)&w_proj,
                    (void*)&b_proj, (void*)&out, (void*)&ws};
    hipError_t err = hipLaunchCooperativeKernel(
        (const void*)k_fused, dim3(coop_grid), dim3(256), args, 0, stream);
    if (err == hipSuccess) return;
    coop_grid = 0;  // disable for subsequent calls
    (void)hipGetLastError();
  }

  // fallback: round-12 four-kernel path (verified 155us)
  __hip_bfloat16* Xb = (__hip_bfloat16*)(ws);
  __hip_bfloat16* WqkvT = (__hip_bfloat16*)(ws + 6291456);
  __hip_bfloat16* WprojT = (__hip_bfloat16*)(ws + 9830400);
  _Float16* Qb = (_Float16*)(ws + 11010048);
  _Float16* Kb = (_Float16*)(ws + 17301504);
  _Float16* VT = (_Float16*)(ws + 23592960);
  unsigned short* ctx = (unsigned short*)(ws + 29884416);

  k_prep_sa<<<5376, 256, 0, stream>>>(x, (unsigned short*)Xb, w_qkv, WqkvT,
                                      w_proj, WprojT);
  k_gemm_sa<0><<<768, 256, 0, stream>>>(Xb, WqkvT, b_qkv, nullptr, Qb, Kb, VT);
  k_attn_sa<<<768, 256, 0, stream>>>(Qb, Kb, VT, ctx);
  k_gemm_sa<1><<<768, 256, 0, stream>>>((const __hip_bfloat16*)ctx, WprojT,
                                        b_proj, out, nullptr, nullptr, nullptr);
}

// Round 10
// 152.359 us; speedup vs baseline: 2.6402x; 2.6402x over previous
//
#include <hip/hip_runtime.h>
#include <hip/hip_bf16.h>

// ---------------------------------------------------------------------------
// MultiHeadAttention forward on MI355X (gfx950). B=2,S=2048,D=768,H=12,Dh=64.
// Masks scale by +1e-9 (numeric no-op) -> full non-causal softmax; dropped.
//
// FINAL (round 15): consolidation on the twice-measured best configuration
// (151.5us prior session / 153.4us round 0). Eleven experiments documented
// across r6-r14 (pipelining, L2-residency swizzles, q-reuse, block geometry,
// V bank-conflict elimination, cooperative fusion) all landed wall-neutral
// (152-155us) or regressed; the wall is set by the serial 4-dispatch
// aggregate + harness memory-state costs, not by any counter-visible pipe.
//
//  * Attention VALU diet: Q pre-scaled by log2(e)/8 (exp2 direct, no arg mul),
//    softmax denominator via mfma(ones, P) (kills 32 adds/iter + final shfls),
//    packed f32->f16 cvt for P.
//  * QKV GEMM 128x96 tiles -> (32,24)=768 blocks = 3/CU exact balance.
//  * Proj GEMM 64x64 tiles -> (64,12)=768 blocks = 3/CU.
//  * Prep (f32->bf16 cast + 2 weight transposes) fused into one launch.
// ---------------------------------------------------------------------------

typedef __attribute__((ext_vector_type(8))) short short8;
typedef __attribute__((ext_vector_type(4))) float float4v;
typedef __attribute__((ext_vector_type(8))) _Float16 half8;
typedef __attribute__((ext_vector_type(4))) _Float16 half4;
typedef __attribute__((ext_vector_type(4))) unsigned short ushort4v;

__device__ __forceinline__ void async_copy16(const void* g, void* l) {
  __builtin_amdgcn_global_load_lds(
      (const __attribute__((address_space(1))) void*)g,
      (__attribute__((address_space(3))) void*)l, 16, 0, 0);
}

__device__ __forceinline__ float fast_exp2(float x) {
#if __has_builtin(__builtin_amdgcn_exp2f)
  return __builtin_amdgcn_exp2f(x);
#else
  return exp2f(x);
#endif
}

__device__ __forceinline__ unsigned short f2bf(float v) {
  __hip_bfloat16 h = __float2bfloat16(v);
  unsigned short u;
  __builtin_memcpy(&u, &h, 2);
  return u;
}

#define LOG2E_8 0.18033688011112042f  // log2(e)/8, folded into Q

// ---- fused prep: x f32->bf16 cast; w_qkv, w_proj transpose->bf16 -----------
__global__ __launch_bounds__(256) void k_prep(
    const float* __restrict__ x, unsigned short* __restrict__ xb,
    const float* __restrict__ wqkv, __hip_bfloat16* __restrict__ wqkvT,
    const float* __restrict__ wproj, __hip_bfloat16* __restrict__ wprojT) {
  __shared__ float tile[32][33];
  const int bid = blockIdx.x, tid = threadIdx.x;
  if (bid < 3072) {  // cast: 4096*768 floats, 4/thread
    int i = bid * 256 + tid;
    float4v v = ((const float4v*)x)[i];
    ushort4v o;
#pragma unroll
    for (int r = 0; r < 4; r++) o[r] = f2bf(v[r]);
    ((ushort4v*)xb)[i] = o;
    return;
  }
  const float* w;
  __hip_bfloat16* wt;
  int N, bx, by;
  if (bid < 4800) {
    int t = bid - 3072; w = wqkv; wt = wqkvT; N = 2304; bx = t % 72; by = t / 72;
  } else {
    int t = bid - 4800; w = wproj; wt = wprojT; N = 768; bx = t % 24; by = t / 24;
  }
  const int n0 = bx * 32, k0 = by * 32;
  const int r = tid >> 5, c = tid & 31;
#pragma unroll
  for (int rr = 0; rr < 32; rr += 8)
    tile[rr + r][c] = w[(long long)(k0 + rr + r) * N + n0 + c];
  __syncthreads();
#pragma unroll
  for (int rr = 0; rr < 32; rr += 8)
    wt[(long long)(n0 + rr + r) * 768 + k0 + c] = __float2bfloat16(tile[c][rr + r]);
}

// ---- bf16 GEMM, BK=64, K=768 (12 iters), conflict-free XOR swizzle ---------
// EPI==0: 128x96 tile; scatter Q(prescaled),K->[B,H,S,64] f16, V->VT (+bias).
// EPI==1: 64x64 tile; out f32 [M][768] = acc + bias.
template <int EPI>
__global__ __launch_bounds__(256) void k_gemm_bt(
    const __hip_bfloat16* __restrict__ A, const __hip_bfloat16* __restrict__ Bt,
    const float* __restrict__ bias, float* __restrict__ outF,
    _Float16* __restrict__ Qb, _Float16* __restrict__ Kb,
    _Float16* __restrict__ VT) {
  constexpr int BM = (EPI == 0) ? 128 : 64;
  constexpr int BN = (EPI == 0) ? 96 : 64;
  constexpr int MT = BM / 32;  // 16-tiles per wave (m)
  constexpr int NT = BN / 32;  // 16-tiles per wave (n)
  __shared__ __align__(16) __hip_bfloat16 At[BM * 64];
  __shared__ __align__(16) __hip_bfloat16 Btl[BN * 64];
  const int tid = threadIdx.x;
  const int w = tid >> 6, l = tid & 63;
  const int quad = l >> 4, lane16 = l & 15;
  const int m0 = blockIdx.x * BM, n0 = blockIdx.y * BN;

  float4v acc[MT][NT];
#pragma unroll
  for (int i = 0; i < MT; i++)
#pragma unroll
    for (int j = 0; j < NT; j++) acc[i][j] = float4v{0.f, 0.f, 0.f, 0.f};

  // staging: call c covers rows c*32..c*32+31; thread t -> row c*32+(t>>3),
  // source granule (t&7)^(row&7); dest = base + t*16B
  const int srow = tid >> 3, sgr = tid & 7;
  const __hip_bfloat16* Asrc = A + (long long)(m0 + srow) * 768 + ((sgr ^ (srow & 7)) * 8);
  const __hip_bfloat16* Bsrc = Bt + (long long)(n0 + srow) * 768 + ((sgr ^ (srow & 7)) * 8);
  __hip_bfloat16* Adst = At + tid * 8;
  __hip_bfloat16* Bdst = Btl + tid * 8;

  const int wr = (w >> 1) * (BM / 2), wc = (w & 1) * (BN / 2);
  const int swz = lane16 & 7;

  for (int kt = 0; kt < 12; kt++) {
    const int k0 = kt * 64;
    __syncthreads();
#pragma unroll
    for (int c = 0; c < BM / 32; c++)
      async_copy16(Asrc + (long long)c * 32 * 768 + k0, Adst + c * 2048);
#pragma unroll
    for (int c = 0; c < BN / 32; c++)
      async_copy16(Bsrc + (long long)c * 32 * 768 + k0, Bdst + c * 2048);
    __syncthreads();
#pragma unroll
    for (int h = 0; h < 2; h++) {
      short8 af[MT], bf[NT];
#pragma unroll
      for (int t = 0; t < MT; t++)
        af[t] = *(const short8*)(At + (wr + t * 16 + lane16) * 64 +
                                 (((h * 4 + quad) ^ swz) * 8));
#pragma unroll
      for (int t = 0; t < NT; t++)
        bf[t] = *(const short8*)(Btl + (wc + t * 16 + lane16) * 64 +
                                 (((h * 4 + quad) ^ swz) * 8));
#pragma unroll
      for (int i = 0; i < MT; i++)
#pragma unroll
        for (int j = 0; j < NT; j++)
          acc[i][j] = __builtin_amdgcn_mfma_f32_16x16x32_bf16(af[i], bf[j], acc[i][j], 0, 0, 0);
    }
  }

  // epilogue: C/D layout col=lane16, row=quad*4+reg
#pragma unroll
  for (int i = 0; i < MT; i++) {
    const int mbase = m0 + wr + i * 16 + quad * 4;
#pragma unroll
    for (int j = 0; j < NT; j++) {
      const int n = n0 + wc + j * 16 + lane16;
      const float bv = bias[n];
      if (EPI == 0) {
        const int which = n / 768;  // uniform across the 16-lane tile
        const int rr = n - which * 768;
        const int hh = rr >> 6, dh = rr & 63;
        const float scale = (which == 0) ? LOG2E_8 : 1.0f;
#pragma unroll
        for (int r = 0; r < 4; r++) {
          const int mm = mbase + r;
          const int b = mm >> 11, s = mm & 2047;
          _Float16 val = (_Float16)((acc[i][j][r] + bv) * scale);
          if (which == 0)
            Qb[((long long)(b * 12 + hh) * 2048 + s) * 64 + dh] = val;
          else if (which == 1)
            Kb[((long long)(b * 12 + hh) * 2048 + s) * 64 + dh] = val;
          else
            VT[((long long)(b * 12 + hh) * 64 + dh) * 2048 + s] = val;
        }
      } else {
#pragma unroll
        for (int r = 0; r < 4; r++)
          outF[(long long)(mbase + r) * 768 + n] = acc[i][j][r] + bv;
      }
    }
  }
}

// ---- attention, f16, S^T formulation, 128-key tiles, MFMA row-sums ---------
// grid (S/64, B*H), 4 waves; wave = 16 q-rows; ctx written bf16 [4096][768].
__global__ __launch_bounds__(256) void k_attn(
    const _Float16* __restrict__ Qb, const _Float16* __restrict__ Kb,
    const _Float16* __restrict__ VT, unsigned short* __restrict__ ctx) {
  __shared__ __align__(16) _Float16 Kl[128 * 64];  // [key][dh], slot g^(r&7)
  __shared__ __align__(16) _Float16 Vl[64 * 128];  // [dh][key], slot g^(r&15)
  const int tid = threadIdx.x, w = tid >> 6, l = tid & 63;
  const int quad = l >> 4, lane16 = l & 15;
  const int bh = blockIdx.y;
  const int q0 = blockIdx.x * 64 + w * 16;
  const _Float16* Qp = Qb + (long long)bh * 2048 * 64;
  const _Float16* Kp = Kb + (long long)bh * 2048 * 64;
  const _Float16* Vp = VT + (long long)bh * 64 * 2048;

  // Q as B-frag of S^T: B[n=q=lane16][k=dh=quad*8+j], two k-halves
  half8 qf[2];
#pragma unroll
  for (int hh = 0; hh < 2; hh++)
    qf[hh] = *(const half8*)(Qp + (q0 + lane16) * 64 + hh * 32 + quad * 8);

  float4v o_acc[4];  // O^T[dh=dt*16+quad*4+r][q=lane16]
#pragma unroll
  for (int t = 0; t < 4; t++) o_acc[t] = float4v{0.f, 0.f, 0.f, 0.f};
  float4v sum_acc = float4v{0.f, 0.f, 0.f, 0.f};  // denominator via mfma(ones,P)
  const half4 ones = {(_Float16)1.f, (_Float16)1.f, (_Float16)1.f, (_Float16)1.f};

  const _Float16* Ksrc = Kp + (long long)(tid >> 3) * 64 + (((tid & 7) ^ ((tid >> 3) & 7)) * 8);
  const _Float16* Vsrc = Vp + (long long)(tid >> 4) * 2048 + ((((tid & 15) ^ (tid >> 4)) & 15) * 8);
  _Float16* Kdst = Kl + tid * 8;
  _Float16* Vdst = Vl + tid * 8;
  const int swz = lane16 & 7;

  for (int kt = 0; kt < 16; kt++) {
    __syncthreads();
#pragma unroll
    for (int c = 0; c < 4; c++) {
      async_copy16(Ksrc + kt * 8192 + c * 2048, Kdst + c * 2048);
      async_copy16(Vsrc + kt * 128 + (long long)c * 16 * 2048, Vdst + c * 2048);
    }
    __syncthreads();

    // S^T = K Q^T : A = K-frag [m=key][k=dh]  (Q carries log2e/8)
    float4v s[8];
#pragma unroll
    for (int kb = 0; kb < 8; kb++) {
      const _Float16* kr = Kl + (kb * 16 + lane16) * 64;
      half8 kf0 = *(const half8*)(kr + ((quad ^ swz) * 8));
      half8 kf1 = *(const half8*)(kr + (((4 + quad) ^ swz) * 8));
      float4v z = float4v{0.f, 0.f, 0.f, 0.f};
      z = __builtin_amdgcn_mfma_f32_16x16x32_f16(kf0, qf[0], z, 0, 0, 0);
      s[kb] = __builtin_amdgcn_mfma_f32_16x16x32_f16(kf1, qf[1], z, 0, 0, 0);
    }
    // p = exp2(s'); P^T packed (pk cvt) as K=16 B-frags (k = quad*4 + r)
    half4 pf[8];
#pragma unroll
    for (int kb = 0; kb < 8; kb++) {
      float p0 = fast_exp2(s[kb][0]);
      float p1 = fast_exp2(s[kb][1]);
      float p2 = fast_exp2(s[kb][2]);
      float p3 = fast_exp2(s[kb][3]);
      auto lo = __builtin_amdgcn_cvt_pkrtz(p0, p1);
      auto hi = __builtin_amdgcn_cvt_pkrtz(p2, p3);
      pf[kb] = half4{static_cast<_Float16>(lo[0]), static_cast<_Float16>(lo[1]),
                     static_cast<_Float16>(hi[0]), static_cast<_Float16>(hi[1])};
    }
    // denominator rows (all rows of D identical = sum over the 16 keys)
#pragma unroll
    for (int kb = 0; kb < 8; kb++)
      sum_acc = __builtin_amdgcn_mfma_f32_16x16x16f16(ones, pf[kb], sum_acc, 0, 0, 0);
    // O^T += V^T P^T : A = V-frag [m=dh][k=key]
#pragma unroll
    for (int dt = 0; dt < 4; dt++) {
      const _Float16* vr = Vl + (dt * 16 + lane16) * 128;
#pragma unroll
      for (int kb = 0; kb < 8; kb++) {
        const int g16 = kb * 2 + (quad >> 1);
        half4 vf = *(const half4*)(vr + ((g16 ^ lane16) * 8) + (quad & 1) * 4);
        o_acc[dt] = __builtin_amdgcn_mfma_f32_16x16x16f16(vf, pf[kb], o_acc[dt], 0, 0, 0);
      }
    }
  }
  // every lane already holds the full denominator for its q=lane16
  const float inv = 1.0f / sum_acc[0];
  const int b = bh / 12, hd = bh - (bh / 12) * 12;
  unsigned short* cp = ctx + ((long long)b * 2048 + q0 + lane16) * 768 + hd * 64 + quad * 4;
#pragma unroll
  for (int dt = 0; dt < 4; dt++) {
    ushort4v cv;
#pragma unroll
    for (int r = 0; r < 4; r++) cv[r] = f2bf(o_acc[dt][r] * inv);
    *(ushort4v*)(cp + dt * 16) = cv;
  }
}

extern "C" void kernel_launch(void* const* d_in, const int* in_sizes, int n_in,
                              void* d_out, int out_size, void* d_ws, size_t ws_size,
                              hipStream_t stream) {
  const float* x = (const float*)d_in[0];
  // d_in[1] attention_mask: masks scaled by +1e-9 -> no-op, dropped
  const float* w_qkv = (const float*)d_in[2];
  const float* b_qkv = (const float*)d_in[3];
  const float* w_proj = (const float*)d_in[4];
  const float* b_proj = (const float*)d_in[5];
  float* out = (float*)d_out;

  char* ws = (char*)d_ws;
  size_t off = 0;
  auto alloc = [&](size_t bytes) {
    void* p = ws + off;
    off += (bytes + 255) & ~(size_t)255;
    return p;
  };
  __hip_bfloat16* Xb = (__hip_bfloat16*)alloc(4096ull * 768 * 2);      // 6.3 MB
  __hip_bfloat16* WqkvT = (__hip_bfloat16*)alloc(2304ull * 768 * 2);   // 3.5 MB
  __hip_bfloat16* WprojT = (__hip_bfloat16*)alloc(768ull * 768 * 2);   // 1.2 MB
  _Float16* Qb = (_Float16*)alloc(3145728ull * 2);                     // 6.3 MB
  _Float16* Kb = (_Float16*)alloc(3145728ull * 2);                     // 6.3 MB
  _Float16* VT = (_Float16*)alloc(3145728ull * 2);                     // 6.3 MB
  __hip_bfloat16* ctx = (__hip_bfloat16*)alloc(4096ull * 768 * 2);     // 6.3 MB

  k_prep<<<5376, 256, 0, stream>>>(x, (unsigned short*)Xb, w_qkv, WqkvT,
                                   w_proj, WprojT);
  k_gemm_bt<0><<<dim3(32, 24), 256, 0, stream>>>(Xb, WqkvT, b_qkv, nullptr,
                                                 Qb, Kb, VT);
  k_attn<<<dim3(32, 24), 256, 0, stream>>>(Qb, Kb, VT, (unsigned short*)ctx);
  k_gemm_bt<1><<<dim3(64, 12), 256, 0, stream>>>(ctx, WprojT, b_proj, out,
                                                 nullptr, nullptr, nullptr);
}